// Round 7
// baseline (256.805 us; speedup 1.0000x reference)
//
#include <hip/hip_runtime.h>

typedef __attribute__((ext_vector_type(8))) short bf16x8_t;
typedef __attribute__((ext_vector_type(4))) float f32x4_t;

#define AS1C(p) ((const __attribute__((address_space(1))) void*)(p))
#define AS3(p)  ((__attribute__((address_space(3))) void*)(p))

#define N_HEAD 12
#define SEQ_T 1024
#define CDIM 768
#define HDIM 64
#define L2E 1.44269504f

__device__ __forceinline__ unsigned short f2bf(float f) {
    union { float f; unsigned int u; } v;
    v.f = f;
    unsigned int r = (v.u + 0x7fffu + ((v.u >> 16) & 1u)) >> 16;
    return (unsigned short)r;
}

// Fused prep: [0,6144) cvt x fp32->bf16; [6144,7872) transpose w_attn; [7872,8448) w_proj.
// One launch instead of three (inter-dispatch gaps ~10us each).
__global__ __launch_bounds__(256) void prep(
    const float4* __restrict__ x4, ushort4* __restrict__ xbf4,
    const float* __restrict__ w_attn, unsigned short* __restrict__ waT,
    const float* __restrict__ w_proj, unsigned short* __restrict__ wpT)
{
    __shared__ float tile[32][33];
    const int blk = blockIdx.x;
    const int tid = threadIdx.x;
    if (blk < 6144) {
        int i = blk * 256 + tid;
        float4 v = x4[i];
        ushort4 o;
        o.x = f2bf(v.x); o.y = f2bf(v.y); o.z = f2bf(v.z); o.w = f2bf(v.w);
        xbf4[i] = o;
        return;
    }
    const float* src; unsigned short* dst; int R, Cc, c0, r0;
    if (blk < 7872) {
        int idx = blk - 6144;           // w_attn: tiles (72 c, 24 r)
        src = w_attn; dst = waT; R = 768; Cc = 2304;
        c0 = (idx % 72) * 32; r0 = (idx / 72) * 32;
    } else {
        int idx = blk - 7872;           // w_proj: tiles (24 c, 24 r)
        src = w_proj; dst = wpT; R = 768; Cc = 768;
        c0 = (idx % 24) * 32; r0 = (idx / 24) * 32;
    }
    const int tx = tid & 31, ty = tid >> 5;
#pragma unroll
    for (int i = 0; i < 4; i++)
        tile[ty + i * 8][tx] = src[(size_t)(r0 + ty + i * 8) * Cc + c0 + tx];
    __syncthreads();
#pragma unroll
    for (int i = 0; i < 4; i++)
        dst[(size_t)(c0 + ty + i * 8) * R + r0 + tx] = f2bf(tile[tx][ty + i * 8]);
}

// 128x128 tile GEMM core, K=768. Async width-16 staging + XOR-granule LDS swizzle.
__device__ __forceinline__ void gemm128_core(
    const unsigned short* __restrict__ A, const unsigned short* __restrict__ Bt,
    unsigned short* As, unsigned short* Bs, f32x4_t acc[4][4], int mBase, int nBase)
{
    const int tid  = threadIdx.x;
    const int lane = tid & 63;
    const int wv   = tid >> 6;
    const int quad = lane >> 4;
    const int l16  = lane & 15;
    const int wm   = (wv >> 1) * 64;
    const int wn   = (wv & 1) * 64;

    f32x4_t zero = {0.f, 0.f, 0.f, 0.f};
#pragma unroll
    for (int tm = 0; tm < 4; tm++)
#pragma unroll
        for (int tn = 0; tn < 4; tn++)
            acc[tm][tn] = zero;

    for (int kt = 0; kt < 768; kt += 64) {
#pragma unroll
        for (int i = 0; i < 4; i++) {
            int cbase = i * 256 + wv * 64;       // wave-uniform chunk base
            int ci = cbase + lane;               // 16B chunk 0..1023
            int r = ci >> 3;
            int koff = (((ci & 7) ^ (r & 7)) << 3);   // swizzled granule
            __builtin_amdgcn_global_load_lds(
                AS1C(A + (size_t)(mBase + r) * 768 + kt + koff),
                AS3(As + cbase * 8), 16, 0, 0);
            __builtin_amdgcn_global_load_lds(
                AS1C(Bt + (size_t)(nBase + r) * 768 + kt + koff),
                AS3(Bs + cbase * 8), 16, 0, 0);
        }
        __syncthreads();
#pragma unroll
        for (int ks = 0; ks < 2; ks++) {
            bf16x8_t af[4], bfv[4];
#pragma unroll
            for (int tm = 0; tm < 4; tm++)
                af[tm] = *(const bf16x8_t*)(As + (wm + tm * 16 + l16) * 64 +
                                            (((ks * 4 + quad) ^ (l16 & 7)) << 3));
#pragma unroll
            for (int tn = 0; tn < 4; tn++)
                bfv[tn] = *(const bf16x8_t*)(Bs + (wn + tn * 16 + l16) * 64 +
                                             (((ks * 4 + quad) ^ (l16 & 7)) << 3));
#pragma unroll
            for (int tm = 0; tm < 4; tm++)
#pragma unroll
                for (int tn = 0; tn < 4; tn++)
                    acc[tm][tn] = __builtin_amdgcn_mfma_f32_16x16x32_bf16(
                        af[tm], bfv[tn], acc[tm][tn], 0, 0, 0);
        }
        __syncthreads();
    }
}

// GEMM1: qkv = x @ w_attn + b_attn. 1D grid 1152, XCD-sliced. 5 blocks/CU target.
__global__ __launch_bounds__(256, 5) void gemm_qkv(
    const unsigned short* __restrict__ x, const unsigned short* __restrict__ waT,
    const float* __restrict__ b_attn,
    unsigned short* __restrict__ qbuf, unsigned short* __restrict__ kbuf,
    unsigned short* __restrict__ vbuf)
{
    __shared__ __align__(16) unsigned short As[128 * 64];
    __shared__ __align__(16) unsigned short Bs[128 * 64];
    f32x4_t acc[4][4];
    const int lid = blockIdx.x;
    const int xcd = lid & 7;
    const int j = lid >> 3;                 // 0..143
    const int mTile = xcd * 8 + (j & 7);    // 0..63
    const int nTile = j >> 3;               // 0..17
    const int mBase = mTile * 128;
    const int nBase = nTile * 128;
    gemm128_core(x, waT, As, Bs, acc, mBase, nBase);

    const int tid = threadIdx.x;
    const int lane = tid & 63, wv = tid >> 6;
    const int quad = lane >> 4, l16 = lane & 15;
    const int wm = (wv >> 1) * 64, wn = (wv & 1) * 64;
    const int part = nTile / 6;             // 0=q 1=k 2=v (block-uniform)

#pragma unroll
    for (int tn = 0; tn < 4; tn++) {
        int n = nBase + wn + tn * 16 + l16;     // 0..2303
        float bv = b_attn[n];
        int f = n - part * 768;
        int hh = f >> 6, d = f & 63;
        if (part == 2) {
#pragma unroll
            for (int tm = 0; tm < 4; tm++) {
                int t0 = mBase + wm + tm * 16 + quad * 4;   // 4-aligned, no b-crossing
                int bb = t0 >> 10, tt = t0 & 1023;
                ushort4 pk;
                pk.x = f2bf(acc[tm][tn][0] + bv);
                pk.y = f2bf(acc[tm][tn][1] + bv);
                pk.z = f2bf(acc[tm][tn][2] + bv);
                pk.w = f2bf(acc[tm][tn][3] + bv);
                *(ushort4*)(vbuf + ((size_t)(bb * N_HEAD + hh) * HDIM + d) * SEQ_T + tt) = pk;
            }
        } else {
            const float scale = (part == 0) ? L2E : 1.f;
            unsigned short* dst = (part == 0) ? qbuf : kbuf;
#pragma unroll
            for (int tm = 0; tm < 4; tm++) {
#pragma unroll
                for (int i = 0; i < 4; i++) {
                    int row = mBase + wm + tm * 16 + quad * 4 + i;
                    int bb = row >> 10, tt = row & 1023;
                    dst[((size_t)(bb * N_HEAD + hh) * SEQ_T + tt) * HDIM + d] =
                        f2bf((acc[tm][tn][i] + bv) * scale);
                }
            }
        }
    }
}

// softmax + PV for one tile, S^T form. s[c][i] holds S^T[s=c*16+quad*4+i][q=l16].
__device__ __forceinline__ void attn_pv(
    f32x4_t s[4], int diag, int qloc, int quad, int l16,
    float& lsum, unsigned short* pw, const bf16x8_t vf[4][2], f32x4_t o[4])
{
    if (diag) {
#pragma unroll
        for (int c = 0; c < 4; c++)
#pragma unroll
            for (int i = 0; i < 4; i++)
                if (c * 16 + quad * 4 + i > qloc) s[c][i] = -1e30f;
    }
    float p[4][4];
#pragma unroll
    for (int c = 0; c < 4; c++)
#pragma unroll
        for (int i = 0; i < 4; i++)
            p[c][i] = exp2f(s[c][i]);
#pragma unroll
    for (int c = 0; c < 4; c++)
        lsum += (p[c][0] + p[c][1]) + (p[c][2] + p[c][3]);

    unsigned int u[4][2];
#pragma unroll
    for (int c = 0; c < 4; c++)
#pragma unroll
        for (int i2 = 0; i2 < 2; i2++)
            u[c][i2] = (unsigned int)f2bf(p[c][2 * i2]) |
                       ((unsigned int)f2bf(p[c][2 * i2 + 1]) << 16);

    __asm__ __volatile__("" ::: "memory");
#pragma unroll
    for (int c = 0; c < 4; c++)
#pragma unroll
        for (int i2 = 0; i2 < 2; i2++) {
            int g = c * 2 + (quad >> 1);
            *(unsigned int*)(pw + l16 * 64 + ((g ^ (l16 & 7)) << 3) +
                             4 * (quad & 1) + 2 * i2) = u[c][i2];
        }
    __asm__ __volatile__("" ::: "memory");
    bf16x8_t pf[2];
#pragma unroll
    for (int kc = 0; kc < 2; kc++)
        pf[kc] = *(const bf16x8_t*)(pw + l16 * 64 + (((kc * 4 + quad) ^ (l16 & 7)) << 3));
    __asm__ __volatile__("" ::: "memory");
#pragma unroll
    for (int kc = 0; kc < 2; kc++)
#pragma unroll
        for (int nc = 0; nc < 4; nc++)
            o[nc] = __builtin_amdgcn_mfma_f32_16x16x32_bf16(pf[kc], vf[nc][kc], o[nc], 0, 0, 0);
}

// Fused causal attention. Block = paired q-tiles (t, 15-t). Grid (96 bh, 8 t):
// lid%8 = bh%8 -> all 8 pair-blocks of a (b,h) share one XCD (K/V hot in its L2).
__global__ __launch_bounds__(256, 4) void attn_fused(
    const unsigned short* __restrict__ qb, const unsigned short* __restrict__ kb,
    const unsigned short* __restrict__ vb, unsigned short* __restrict__ attb)
{
    __shared__ __align__(16) unsigned short Kbuf[2][64 * 64];
    __shared__ __align__(16) unsigned short Vbuf[2][64 * 64];   // V^T tiles [d][s]
    __shared__ __align__(16) unsigned short Psh[4][16 * 64];

    const int bhx = blockIdx.x;     // 0..95
    const int t   = blockIdx.y;     // 0..7; tiles t and 15-t
    const int h = bhx % N_HEAD;
    const int b = bhx / N_HEAD;
    const int tid = threadIdx.x;
    const int lane = tid & 63, wv = tid >> 6;
    const int quad = lane >> 4, l16 = lane & 15;
    const int tB = 15 - t, kmax = 15 - t;
    const int qloc = wv * 16 + l16;

    const size_t bh = (size_t)(b * N_HEAD + h);
    const unsigned short* kbase = kb + bh * SEQ_T * HDIM;
    const unsigned short* vbase = vb + bh * HDIM * SEQ_T;
    const unsigned short* qpt   = qb + bh * SEQ_T * HDIM;

    const int j0 = wv * 128 + lane, j1 = j0 + 64;
    const int r0 = j0 >> 3, g0 = (j0 & 7) ^ (r0 & 7);
    const int r1 = j1 >> 3, g1 = (j1 & 7) ^ (r1 & 7);
    const int rgK0 = r0 * 64 + g0 * 8,   rgK1 = r1 * 64 + g1 * 8;
    const int rgV0 = r0 * 1024 + g0 * 8, rgV1 = r1 * 1024 + g1 * 8;
    const int ldsc0 = (wv * 128) * 8, ldsc1 = (wv * 128 + 64) * 8;  // wave-uniform

    bf16x8_t qfA[2], qfB[2];
    {
        const unsigned short* qa  = qpt + (size_t)(t * 64 + qloc) * HDIM;
        const unsigned short* qbp = qpt + (size_t)(tB * 64 + qloc) * HDIM;
#pragma unroll
        for (int kc = 0; kc < 2; kc++) {
            qfA[kc] = *(const bf16x8_t*)(qa + kc * 32 + quad * 8);
            qfB[kc] = *(const bf16x8_t*)(qbp + kc * 32 + quad * 8);
        }
    }

    f32x4_t zero = {0.f, 0.f, 0.f, 0.f};
    f32x4_t oA[4], oB[4];
#pragma unroll
    for (int c = 0; c < 4; c++) { oA[c] = zero; oB[c] = zero; }
    float lA = 0.f, lB = 0.f;

    __builtin_amdgcn_global_load_lds(AS1C(kbase + rgK0), AS3(&Kbuf[0][0] + ldsc0), 16, 0, 0);
    __builtin_amdgcn_global_load_lds(AS1C(kbase + rgK1), AS3(&Kbuf[0][0] + ldsc1), 16, 0, 0);
    __builtin_amdgcn_global_load_lds(AS1C(vbase + rgV0), AS3(&Vbuf[0][0] + ldsc0), 16, 0, 0);
    __builtin_amdgcn_global_load_lds(AS1C(vbase + rgV1), AS3(&Vbuf[0][0] + ldsc1), 16, 0, 0);
    __syncthreads();

    for (int kt = 0; kt <= kmax; kt++) {
        const int cur = kt & 1, nxt = cur ^ 1;
        if (kt < kmax) {
            const unsigned short* kp = kbase + (kt + 1) * 4096;
            const unsigned short* vp = vbase + (kt + 1) * 64;
            __builtin_amdgcn_global_load_lds(AS1C(kp + rgK0), AS3(&Kbuf[nxt][0] + ldsc0), 16, 0, 0);
            __builtin_amdgcn_global_load_lds(AS1C(kp + rgK1), AS3(&Kbuf[nxt][0] + ldsc1), 16, 0, 0);
            __builtin_amdgcn_global_load_lds(AS1C(vp + rgV0), AS3(&Vbuf[nxt][0] + ldsc0), 16, 0, 0);
            __builtin_amdgcn_global_load_lds(AS1C(vp + rgV1), AS3(&Vbuf[nxt][0] + ldsc1), 16, 0, 0);
        }

        const unsigned short* Kc = &Kbuf[cur][0];
        const unsigned short* Vc = &Vbuf[cur][0];
        const int doA = (kt <= t);

        bf16x8_t vf[4][2];
#pragma unroll
        for (int nc = 0; nc < 4; nc++)
#pragma unroll
            for (int kc = 0; kc < 2; kc++)
                vf[nc][kc] = *(const bf16x8_t*)(Vc + (nc * 16 + l16) * 64 +
                                                (((kc * 4 + quad) ^ (l16 & 7)) << 3));

        f32x4_t sB[4], sA[4];
#pragma unroll
        for (int c = 0; c < 4; c++) {
            bf16x8_t kf0 = *(const bf16x8_t*)(Kc + (c * 16 + l16) * 64 +
                                              ((quad ^ (l16 & 7)) << 3));
            bf16x8_t kf1 = *(const bf16x8_t*)(Kc + (c * 16 + l16) * 64 +
                                              (((4 + quad) ^ (l16 & 7)) << 3));
            sB[c] = __builtin_amdgcn_mfma_f32_16x16x32_bf16(kf0, qfB[0], zero, 0, 0, 0);
            sB[c] = __builtin_amdgcn_mfma_f32_16x16x32_bf16(kf1, qfB[1], sB[c], 0, 0, 0);
            if (doA) {
                sA[c] = __builtin_amdgcn_mfma_f32_16x16x32_bf16(kf0, qfA[0], zero, 0, 0, 0);
                sA[c] = __builtin_amdgcn_mfma_f32_16x16x32_bf16(kf1, qfA[1], sA[c], 0, 0, 0);
            }
        }

        unsigned short* pw = &Psh[wv][0];
        attn_pv(sB, kt == tB, qloc, quad, l16, lB, pw, vf, oB);
        if (doA)
            attn_pv(sA, kt == t, qloc, quad, l16, lA, pw, vf, oA);
        __syncthreads();
    }

    lA += __shfl_xor(lA, 16); lA += __shfl_xor(lA, 32);
    lB += __shfl_xor(lB, 16); lB += __shfl_xor(lB, 32);
    float invA = 1.f / lA, invB = 1.f / lB;
    float iA[4], iB[4];
#pragma unroll
    for (int i = 0; i < 4; i++) {
        iA[i] = __shfl(invA, quad * 4 + i);
        iB[i] = __shfl(invB, quad * 4 + i);
    }

#pragma unroll
    for (int nc = 0; nc < 4; nc++)
#pragma unroll
        for (int i = 0; i < 4; i++) {
            int rowA = t * 64 + wv * 16 + quad * 4 + i;
            int rowB = tB * 64 + wv * 16 + quad * 4 + i;
            int col = h * HDIM + nc * 16 + l16;
            attb[((size_t)b * SEQ_T + rowA) * CDIM + col] = f2bf(oA[nc][i] * iA[i]);
            attb[((size_t)b * SEQ_T + rowB) * CDIM + col] = f2bf(oB[nc][i] * iB[i]);
        }
}

// GEMM2: out(fp32) = att @ w_proj + b_proj. 1D grid 384, XCD-sliced like gemm_qkv.
__global__ __launch_bounds__(256) void gemm_proj(
    const unsigned short* __restrict__ attb, const unsigned short* __restrict__ wpT,
    const float* __restrict__ b_proj, float* __restrict__ out)
{
    __shared__ __align__(16) unsigned short As[128 * 64];
    __shared__ __align__(16) unsigned short Bs[128 * 64];
    f32x4_t acc[4][4];
    const int lid = blockIdx.x;
    const int xcd = lid & 7;
    const int j = lid >> 3;                 // 0..47
    const int mTile = xcd * 8 + (j & 7);    // 0..63
    const int nTile = j >> 3;               // 0..5
    const int mBase = mTile * 128;
    const int nBase = nTile * 128;
    gemm128_core(attb, wpT, As, Bs, acc, mBase, nBase);

    const int tid = threadIdx.x;
    const int lane = tid & 63, wv = tid >> 6;
    const int quad = lane >> 4, l16 = lane & 15;
    const int wm = (wv >> 1) * 64, wn = (wv & 1) * 64;

#pragma unroll
    for (int tn = 0; tn < 4; tn++) {
        int n = nBase + wn + tn * 16 + l16;
        float bv = b_proj[n];
#pragma unroll
        for (int tm = 0; tm < 4; tm++)
#pragma unroll
            for (int i = 0; i < 4; i++) {
                int row = mBase + wm + tm * 16 + quad * 4 + i;
                out[(size_t)row * CDIM + n] = acc[tm][tn][i] + bv;
            }
    }
}

extern "C" void kernel_launch(void* const* d_in, const int* in_sizes, int n_in,
                              void* d_out, int out_size, void* d_ws, size_t ws_size,
                              hipStream_t stream) {
    const float* x      = (const float*)d_in[0];  // [8,1024,768] fp32
    const float* w_attn = (const float*)d_in[1];  // [768,2304]   fp32
    const float* b_attn = (const float*)d_in[2];  // [2304]       fp32
    const float* w_proj = (const float*)d_in[3];  // [768,768]    fp32
    const float* b_proj = (const float*)d_in[4];  // [768]        fp32
    float* out = (float*)d_out;                   // [8,1024,768] fp32

    unsigned short* ws   = (unsigned short*)d_ws;
    unsigned short* waT  = ws;                    // [2304][768] bf16
    unsigned short* wpT  = waT + 1769472;         // [768][768]  bf16
    unsigned short* xbf  = wpT + 589824;          // [8192][768] bf16
    unsigned short* qbuf = xbf + 6291456;         // [B,H,T,D] (log2e-scaled)
    unsigned short* kbuf = qbuf + 6291456;        // [B,H,T,D]
    unsigned short* vbuf = kbuf + 6291456;        // [B,H,D,T]
    unsigned short* attb = vbuf + 6291456;        // [B,T,C]
    // ws use: 67,633,152 bytes

    prep<<<dim3(8448), 256, 0, stream>>>((const float4*)x, (ushort4*)xbf,
                                         w_attn, waT, w_proj, wpT);
    gemm_qkv<<<dim3(1152), 256, 0, stream>>>(xbf, waT, b_attn, qbuf, kbuf, vbuf);
    attn_fused<<<dim3(96, 8), 256, 0, stream>>>(qbuf, kbuf, vbuf, attb);
    gemm_proj<<<dim3(384), 256, 0, stream>>>(attb, wpT, b_proj, out);
}

// Round 8
// 188.553 us; speedup vs baseline: 1.3620x; 1.3620x over previous
//
#include <hip/hip_runtime.h>

typedef __attribute__((ext_vector_type(8))) short bf16x8_t;
typedef __attribute__((ext_vector_type(4))) float f32x4_t;

#define AS1C(p) ((const __attribute__((address_space(1))) void*)(p))
#define AS3(p)  ((__attribute__((address_space(3))) void*)(p))

#define N_HEAD 12
#define SEQ_T 1024
#define CDIM 768
#define HDIM 64
#define L2E 1.44269504f

__device__ __forceinline__ unsigned short f2bf(float f) {
    union { float f; unsigned int u; } v;
    v.f = f;
    unsigned int r = (v.u + 0x7fffu + ((v.u >> 16) & 1u)) >> 16;
    return (unsigned short)r;
}

// Fused prep: [0,6144) cvt x fp32->bf16; [6144,7872) transpose w_attn; [7872,8448) w_proj.
__global__ __launch_bounds__(256) void prep(
    const float4* __restrict__ x4, ushort4* __restrict__ xbf4,
    const float* __restrict__ w_attn, unsigned short* __restrict__ waT,
    const float* __restrict__ w_proj, unsigned short* __restrict__ wpT)
{
    __shared__ float tile[32][33];
    const int blk = blockIdx.x;
    const int tid = threadIdx.x;
    if (blk < 6144) {
        int i = blk * 256 + tid;
        float4 v = x4[i];
        ushort4 o;
        o.x = f2bf(v.x); o.y = f2bf(v.y); o.z = f2bf(v.z); o.w = f2bf(v.w);
        xbf4[i] = o;
        return;
    }
    const float* src; unsigned short* dst; int R, Cc, c0, r0;
    if (blk < 7872) {
        int idx = blk - 6144;           // w_attn: tiles (72 c, 24 r)
        src = w_attn; dst = waT; R = 768; Cc = 2304;
        c0 = (idx % 72) * 32; r0 = (idx / 72) * 32;
    } else {
        int idx = blk - 7872;           // w_proj: tiles (24 c, 24 r)
        src = w_proj; dst = wpT; R = 768; Cc = 768;
        c0 = (idx % 24) * 32; r0 = (idx / 24) * 32;
    }
    const int tx = tid & 31, ty = tid >> 5;
#pragma unroll
    for (int i = 0; i < 4; i++)
        tile[ty + i * 8][tx] = src[(size_t)(r0 + ty + i * 8) * Cc + c0 + tx];
    __syncthreads();
#pragma unroll
    for (int i = 0; i < 4; i++)
        dst[(size_t)(c0 + ty + i * 8) * R + r0 + tx] = f2bf(tile[tx][ty + i * 8]);
}

// 128x128 tile GEMM core, K=768. Async width-16 staging + XOR-granule LDS swizzle.
__device__ __forceinline__ void gemm128_core(
    const unsigned short* __restrict__ A, const unsigned short* __restrict__ Bt,
    unsigned short* As, unsigned short* Bs, f32x4_t acc[4][4], int mBase, int nBase)
{
    const int tid  = threadIdx.x;
    const int lane = tid & 63;
    const int wv   = tid >> 6;
    const int quad = lane >> 4;
    const int l16  = lane & 15;
    const int wm   = (wv >> 1) * 64;
    const int wn   = (wv & 1) * 64;

    f32x4_t zero = {0.f, 0.f, 0.f, 0.f};
#pragma unroll
    for (int tm = 0; tm < 4; tm++)
#pragma unroll
        for (int tn = 0; tn < 4; tn++)
            acc[tm][tn] = zero;

    for (int kt = 0; kt < 768; kt += 64) {
#pragma unroll
        for (int i = 0; i < 4; i++) {
            int cbase = i * 256 + wv * 64;       // wave-uniform chunk base
            int ci = cbase + lane;               // 16B chunk 0..1023
            int r = ci >> 3;
            int koff = (((ci & 7) ^ (r & 7)) << 3);   // swizzled granule
            __builtin_amdgcn_global_load_lds(
                AS1C(A + (size_t)(mBase + r) * 768 + kt + koff),
                AS3(As + cbase * 8), 16, 0, 0);
            __builtin_amdgcn_global_load_lds(
                AS1C(Bt + (size_t)(nBase + r) * 768 + kt + koff),
                AS3(Bs + cbase * 8), 16, 0, 0);
        }
        __syncthreads();
#pragma unroll
        for (int ks = 0; ks < 2; ks++) {
            bf16x8_t af[4], bfv[4];
#pragma unroll
            for (int tm = 0; tm < 4; tm++)
                af[tm] = *(const bf16x8_t*)(As + (wm + tm * 16 + l16) * 64 +
                                            (((ks * 4 + quad) ^ (l16 & 7)) << 3));
#pragma unroll
            for (int tn = 0; tn < 4; tn++)
                bfv[tn] = *(const bf16x8_t*)(Bs + (wn + tn * 16 + l16) * 64 +
                                             (((ks * 4 + quad) ^ (l16 & 7)) << 3));
#pragma unroll
            for (int tm = 0; tm < 4; tm++)
#pragma unroll
                for (int tn = 0; tn < 4; tn++)
                    acc[tm][tn] = __builtin_amdgcn_mfma_f32_16x16x32_bf16(
                        af[tm], bfv[tn], acc[tm][tn], 0, 0, 0);
        }
        __syncthreads();
    }
}

// GEMM1: qkv = x @ w_attn + b_attn. 1D grid 1152, XCD-sliced.
// NOTE: no min-waves bound — (256,5) forced VGPR 112->48 and spilled
// (WRITE_SIZE 37->73 MB, dur 57->90 us). Natural allocation is 112.
__global__ __launch_bounds__(256) void gemm_qkv(
    const unsigned short* __restrict__ x, const unsigned short* __restrict__ waT,
    const float* __restrict__ b_attn,
    unsigned short* __restrict__ qbuf, unsigned short* __restrict__ kbuf,
    unsigned short* __restrict__ vbuf)
{
    __shared__ __align__(16) unsigned short As[128 * 64];
    __shared__ __align__(16) unsigned short Bs[128 * 64];
    f32x4_t acc[4][4];
    const int lid = blockIdx.x;
    const int xcd = lid & 7;
    const int j = lid >> 3;                 // 0..143
    const int mTile = xcd * 8 + (j & 7);    // 0..63
    const int nTile = j >> 3;               // 0..17
    const int mBase = mTile * 128;
    const int nBase = nTile * 128;
    gemm128_core(x, waT, As, Bs, acc, mBase, nBase);

    const int tid = threadIdx.x;
    const int lane = tid & 63, wv = tid >> 6;
    const int quad = lane >> 4, l16 = lane & 15;
    const int wm = (wv >> 1) * 64, wn = (wv & 1) * 64;
    const int part = nTile / 6;             // 0=q 1=k 2=v (block-uniform)

#pragma unroll
    for (int tn = 0; tn < 4; tn++) {
        int n = nBase + wn + tn * 16 + l16;     // 0..2303
        float bv = b_attn[n];
        int f = n - part * 768;
        int hh = f >> 6, d = f & 63;
        if (part == 2) {
#pragma unroll
            for (int tm = 0; tm < 4; tm++) {
                int t0 = mBase + wm + tm * 16 + quad * 4;   // 4-aligned, no b-crossing
                int bb = t0 >> 10, tt = t0 & 1023;
                ushort4 pk;
                pk.x = f2bf(acc[tm][tn][0] + bv);
                pk.y = f2bf(acc[tm][tn][1] + bv);
                pk.z = f2bf(acc[tm][tn][2] + bv);
                pk.w = f2bf(acc[tm][tn][3] + bv);
                *(ushort4*)(vbuf + ((size_t)(bb * N_HEAD + hh) * HDIM + d) * SEQ_T + tt) = pk;
            }
        } else {
            const float scale = (part == 0) ? L2E : 1.f;
            unsigned short* dst = (part == 0) ? qbuf : kbuf;
#pragma unroll
            for (int tm = 0; tm < 4; tm++) {
#pragma unroll
                for (int i = 0; i < 4; i++) {
                    int row = mBase + wm + tm * 16 + quad * 4 + i;
                    int bb = row >> 10, tt = row & 1023;
                    dst[((size_t)(bb * N_HEAD + hh) * SEQ_T + tt) * HDIM + d] =
                        f2bf((acc[tm][tn][i] + bv) * scale);
                }
            }
        }
    }
}

// softmax + PV for one tile, S^T form. s[c][i] holds S^T[s=c*16+quad*4+i][q=l16].
__device__ __forceinline__ void attn_pv(
    f32x4_t s[4], int diag, int qloc, int quad, int l16,
    float& lsum, unsigned short* pw, const bf16x8_t vf[4][2], f32x4_t o[4])
{
    if (diag) {
#pragma unroll
        for (int c = 0; c < 4; c++)
#pragma unroll
            for (int i = 0; i < 4; i++)
                if (c * 16 + quad * 4 + i > qloc) s[c][i] = -1e30f;
    }
    float p[4][4];
#pragma unroll
    for (int c = 0; c < 4; c++)
#pragma unroll
        for (int i = 0; i < 4; i++)
            p[c][i] = exp2f(s[c][i]);
#pragma unroll
    for (int c = 0; c < 4; c++)
        lsum += (p[c][0] + p[c][1]) + (p[c][2] + p[c][3]);

    unsigned int u[4][2];
#pragma unroll
    for (int c = 0; c < 4; c++)
#pragma unroll
        for (int i2 = 0; i2 < 2; i2++)
            u[c][i2] = (unsigned int)f2bf(p[c][2 * i2]) |
                       ((unsigned int)f2bf(p[c][2 * i2 + 1]) << 16);

    __asm__ __volatile__("" ::: "memory");
#pragma unroll
    for (int c = 0; c < 4; c++)
#pragma unroll
        for (int i2 = 0; i2 < 2; i2++) {
            int g = c * 2 + (quad >> 1);
            *(unsigned int*)(pw + l16 * 64 + ((g ^ (l16 & 7)) << 3) +
                             4 * (quad & 1) + 2 * i2) = u[c][i2];
        }
    __asm__ __volatile__("" ::: "memory");
    bf16x8_t pf[2];
#pragma unroll
    for (int kc = 0; kc < 2; kc++)
        pf[kc] = *(const bf16x8_t*)(pw + l16 * 64 + (((kc * 4 + quad) ^ (l16 & 7)) << 3));
    __asm__ __volatile__("" ::: "memory");
#pragma unroll
    for (int kc = 0; kc < 2; kc++)
#pragma unroll
        for (int nc = 0; nc < 4; nc++)
            o[nc] = __builtin_amdgcn_mfma_f32_16x16x32_bf16(pf[kc], vf[nc][kc], o[nc], 0, 0, 0);
}

// Fused causal attention. Block = paired q-tiles (t, 15-t). Grid (96 bh, 8 t):
// lid%8 = bh%8 -> all 8 pair-blocks of a (b,h) share one XCD (K/V hot in its L2).
__global__ __launch_bounds__(256, 3) void attn_fused(
    const unsigned short* __restrict__ qb, const unsigned short* __restrict__ kb,
    const unsigned short* __restrict__ vb, unsigned short* __restrict__ attb)
{
    __shared__ __align__(16) unsigned short Kbuf[2][64 * 64];
    __shared__ __align__(16) unsigned short Vbuf[2][64 * 64];   // V^T tiles [d][s]
    __shared__ __align__(16) unsigned short Psh[4][16 * 64];

    const int bhx = blockIdx.x;     // 0..95
    const int t   = blockIdx.y;     // 0..7; tiles t and 15-t
    const int h = bhx % N_HEAD;
    const int b = bhx / N_HEAD;
    const int tid = threadIdx.x;
    const int lane = tid & 63, wv = tid >> 6;
    const int quad = lane >> 4, l16 = lane & 15;
    const int tB = 15 - t, kmax = 15 - t;
    const int qloc = wv * 16 + l16;

    const size_t bh = (size_t)(b * N_HEAD + h);
    const unsigned short* kbase = kb + bh * SEQ_T * HDIM;
    const unsigned short* vbase = vb + bh * HDIM * SEQ_T;
    const unsigned short* qpt   = qb + bh * SEQ_T * HDIM;

    const int j0 = wv * 128 + lane, j1 = j0 + 64;
    const int r0 = j0 >> 3, g0 = (j0 & 7) ^ (r0 & 7);
    const int r1 = j1 >> 3, g1 = (j1 & 7) ^ (r1 & 7);
    const int rgK0 = r0 * 64 + g0 * 8,   rgK1 = r1 * 64 + g1 * 8;
    const int rgV0 = r0 * 1024 + g0 * 8, rgV1 = r1 * 1024 + g1 * 8;
    const int ldsc0 = (wv * 128) * 8, ldsc1 = (wv * 128 + 64) * 8;  // wave-uniform

    bf16x8_t qfA[2], qfB[2];
    {
        const unsigned short* qa  = qpt + (size_t)(t * 64 + qloc) * HDIM;
        const unsigned short* qbp = qpt + (size_t)(tB * 64 + qloc) * HDIM;
#pragma unroll
        for (int kc = 0; kc < 2; kc++) {
            qfA[kc] = *(const bf16x8_t*)(qa + kc * 32 + quad * 8);
            qfB[kc] = *(const bf16x8_t*)(qbp + kc * 32 + quad * 8);
        }
    }

    f32x4_t zero = {0.f, 0.f, 0.f, 0.f};
    f32x4_t oA[4], oB[4];
#pragma unroll
    for (int c = 0; c < 4; c++) { oA[c] = zero; oB[c] = zero; }
    float lA = 0.f, lB = 0.f;

    __builtin_amdgcn_global_load_lds(AS1C(kbase + rgK0), AS3(&Kbuf[0][0] + ldsc0), 16, 0, 0);
    __builtin_amdgcn_global_load_lds(AS1C(kbase + rgK1), AS3(&Kbuf[0][0] + ldsc1), 16, 0, 0);
    __builtin_amdgcn_global_load_lds(AS1C(vbase + rgV0), AS3(&Vbuf[0][0] + ldsc0), 16, 0, 0);
    __builtin_amdgcn_global_load_lds(AS1C(vbase + rgV1), AS3(&Vbuf[0][0] + ldsc1), 16, 0, 0);
    __syncthreads();

    for (int kt = 0; kt <= kmax; kt++) {
        const int cur = kt & 1, nxt = cur ^ 1;
        if (kt < kmax) {
            const unsigned short* kp = kbase + (kt + 1) * 4096;
            const unsigned short* vp = vbase + (kt + 1) * 64;
            __builtin_amdgcn_global_load_lds(AS1C(kp + rgK0), AS3(&Kbuf[nxt][0] + ldsc0), 16, 0, 0);
            __builtin_amdgcn_global_load_lds(AS1C(kp + rgK1), AS3(&Kbuf[nxt][0] + ldsc1), 16, 0, 0);
            __builtin_amdgcn_global_load_lds(AS1C(vp + rgV0), AS3(&Vbuf[nxt][0] + ldsc0), 16, 0, 0);
            __builtin_amdgcn_global_load_lds(AS1C(vp + rgV1), AS3(&Vbuf[nxt][0] + ldsc1), 16, 0, 0);
        }

        const unsigned short* Kc = &Kbuf[cur][0];
        const unsigned short* Vc = &Vbuf[cur][0];
        const int doA = (kt <= t);

        bf16x8_t vf[4][2];
#pragma unroll
        for (int nc = 0; nc < 4; nc++)
#pragma unroll
            for (int kc = 0; kc < 2; kc++)
                vf[nc][kc] = *(const bf16x8_t*)(Vc + (nc * 16 + l16) * 64 +
                                                (((kc * 4 + quad) ^ (l16 & 7)) << 3));

        f32x4_t sB[4], sA[4];
#pragma unroll
        for (int c = 0; c < 4; c++) {
            bf16x8_t kf0 = *(const bf16x8_t*)(Kc + (c * 16 + l16) * 64 +
                                              ((quad ^ (l16 & 7)) << 3));
            bf16x8_t kf1 = *(const bf16x8_t*)(Kc + (c * 16 + l16) * 64 +
                                              (((4 + quad) ^ (l16 & 7)) << 3));
            sB[c] = __builtin_amdgcn_mfma_f32_16x16x32_bf16(kf0, qfB[0], zero, 0, 0, 0);
            sB[c] = __builtin_amdgcn_mfma_f32_16x16x32_bf16(kf1, qfB[1], sB[c], 0, 0, 0);
            if (doA) {
                sA[c] = __builtin_amdgcn_mfma_f32_16x16x32_bf16(kf0, qfA[0], zero, 0, 0, 0);
                sA[c] = __builtin_amdgcn_mfma_f32_16x16x32_bf16(kf1, qfA[1], sA[c], 0, 0, 0);
            }
        }

        unsigned short* pw = &Psh[wv][0];
        attn_pv(sB, kt == tB, qloc, quad, l16, lB, pw, vf, oB);
        if (doA)
            attn_pv(sA, kt == t, qloc, quad, l16, lA, pw, vf, oA);
        __syncthreads();
    }

    lA += __shfl_xor(lA, 16); lA += __shfl_xor(lA, 32);
    lB += __shfl_xor(lB, 16); lB += __shfl_xor(lB, 32);
    float invA = 1.f / lA, invB = 1.f / lB;
    float iA[4], iB[4];
#pragma unroll
    for (int i = 0; i < 4; i++) {
        iA[i] = __shfl(invA, quad * 4 + i);
        iB[i] = __shfl(invB, quad * 4 + i);
    }

#pragma unroll
    for (int nc = 0; nc < 4; nc++)
#pragma unroll
        for (int i = 0; i < 4; i++) {
            int rowA = t * 64 + wv * 16 + quad * 4 + i;
            int rowB = tB * 64 + wv * 16 + quad * 4 + i;
            int col = h * HDIM + nc * 16 + l16;
            attb[((size_t)b * SEQ_T + rowA) * CDIM + col] = f2bf(oA[nc][i] * iA[i]);
            attb[((size_t)b * SEQ_T + rowB) * CDIM + col] = f2bf(oB[nc][i] * iB[i]);
        }
}

// GEMM2: out(fp32) = att @ w_proj + b_proj. 1D grid 384, XCD-sliced like gemm_qkv.
__global__ __launch_bounds__(256) void gemm_proj(
    const unsigned short* __restrict__ attb, const unsigned short* __restrict__ wpT,
    const float* __restrict__ b_proj, float* __restrict__ out)
{
    __shared__ __align__(16) unsigned short As[128 * 64];
    __shared__ __align__(16) unsigned short Bs[128 * 64];
    f32x4_t acc[4][4];
    const int lid = blockIdx.x;
    const int xcd = lid & 7;
    const int j = lid >> 3;                 // 0..47
    const int mTile = xcd * 8 + (j & 7);    // 0..63
    const int nTile = j >> 3;               // 0..5
    const int mBase = mTile * 128;
    const int nBase = nTile * 128;
    gemm128_core(attb, wpT, As, Bs, acc, mBase, nBase);

    const int tid = threadIdx.x;
    const int lane = tid & 63, wv = tid >> 6;
    const int quad = lane >> 4, l16 = lane & 15;
    const int wm = (wv >> 1) * 64, wn = (wv & 1) * 64;

#pragma unroll
    for (int tn = 0; tn < 4; tn++) {
        int n = nBase + wn + tn * 16 + l16;
        float bv = b_proj[n];
#pragma unroll
        for (int tm = 0; tm < 4; tm++)
#pragma unroll
            for (int i = 0; i < 4; i++) {
                int row = mBase + wm + tm * 16 + quad * 4 + i;
                out[(size_t)row * CDIM + n] = acc[tm][tn][i] + bv;
            }
    }
}

extern "C" void kernel_launch(void* const* d_in, const int* in_sizes, int n_in,
                              void* d_out, int out_size, void* d_ws, size_t ws_size,
                              hipStream_t stream) {
    const float* x      = (const float*)d_in[0];  // [8,1024,768] fp32
    const float* w_attn = (const float*)d_in[1];  // [768,2304]   fp32
    const float* b_attn = (const float*)d_in[2];  // [2304]       fp32
    const float* w_proj = (const float*)d_in[3];  // [768,768]    fp32
    const float* b_proj = (const float*)d_in[4];  // [768]        fp32
    float* out = (float*)d_out;                   // [8,1024,768] fp32

    unsigned short* ws   = (unsigned short*)d_ws;
    unsigned short* waT  = ws;                    // [2304][768] bf16
    unsigned short* wpT  = waT + 1769472;         // [768][768]  bf16
    unsigned short* xbf  = wpT + 589824;          // [8192][768] bf16
    unsigned short* qbuf = xbf + 6291456;         // [B,H,T,D] (log2e-scaled)
    unsigned short* kbuf = qbuf + 6291456;        // [B,H,T,D]
    unsigned short* vbuf = kbuf + 6291456;        // [B,H,D,T]
    unsigned short* attb = vbuf + 6291456;        // [B,T,C]
    // ws use: 67,633,152 bytes

    prep<<<dim3(8448), 256, 0, stream>>>((const float4*)x, (ushort4*)xbf,
                                         w_attn, waT, w_proj, wpT);
    gemm_qkv<<<dim3(1152), 256, 0, stream>>>(xbf, waT, b_attn, qbuf, kbuf, vbuf);
    attn_fused<<<dim3(96, 8), 256, 0, stream>>>(qbuf, kbuf, vbuf, attb);
    gemm_proj<<<dim3(384), 256, 0, stream>>>(attb, wpT, b_proj, out);
}

// Round 10
// 187.493 us; speedup vs baseline: 1.3697x; 1.0057x over previous
//
#include <hip/hip_runtime.h>

typedef __attribute__((ext_vector_type(8))) short bf16x8_t;
typedef __attribute__((ext_vector_type(4))) float f32x4_t;

#define AS1C(p) ((const __attribute__((address_space(1))) void*)(p))
#define AS3(p)  ((__attribute__((address_space(3))) void*)(p))

#define N_HEAD 12
#define SEQ_T 1024
#define CDIM 768
#define HDIM 64
#define L2E 1.44269504f

__device__ __forceinline__ unsigned short f2bf(float f) {
    union { float f; unsigned int u; } v;
    v.f = f;
    unsigned int r = (v.u + 0x7fffu + ((v.u >> 16) & 1u)) >> 16;
    return (unsigned short)r;
}

// Fused prep: [0,6144) cvt x fp32->bf16; [6144,7872) transpose w_attn; [7872,8448) w_proj.
__global__ __launch_bounds__(256) void prep(
    const float4* __restrict__ x4, ushort4* __restrict__ xbf4,
    const float* __restrict__ w_attn, unsigned short* __restrict__ waT,
    const float* __restrict__ w_proj, unsigned short* __restrict__ wpT)
{
    __shared__ float tile[32][33];
    const int blk = blockIdx.x;
    const int tid = threadIdx.x;
    if (blk < 6144) {
        int i = blk * 256 + tid;
        float4 v = x4[i];
        ushort4 o;
        o.x = f2bf(v.x); o.y = f2bf(v.y); o.z = f2bf(v.z); o.w = f2bf(v.w);
        xbf4[i] = o;
        return;
    }
    const float* src; unsigned short* dst; int R, Cc, c0, r0;
    if (blk < 7872) {
        int idx = blk - 6144;           // w_attn: tiles (72 c, 24 r)
        src = w_attn; dst = waT; R = 768; Cc = 2304;
        c0 = (idx % 72) * 32; r0 = (idx / 72) * 32;
    } else {
        int idx = blk - 7872;           // w_proj: tiles (24 c, 24 r)
        src = w_proj; dst = wpT; R = 768; Cc = 768;
        c0 = (idx % 24) * 32; r0 = (idx / 24) * 32;
    }
    const int tx = tid & 31, ty = tid >> 5;
#pragma unroll
    for (int i = 0; i < 4; i++)
        tile[ty + i * 8][tx] = src[(size_t)(r0 + ty + i * 8) * Cc + c0 + tx];
    __syncthreads();
#pragma unroll
    for (int i = 0; i < 4; i++)
        dst[(size_t)(c0 + ty + i * 8) * R + r0 + tx] = f2bf(tile[tx][ty + i * 8]);
}

// 128x128 tile GEMM core, K=768. Async width-16 staging + XOR-granule LDS swizzle.
__device__ __forceinline__ void gemm128_core(
    const unsigned short* __restrict__ A, const unsigned short* __restrict__ Bt,
    unsigned short* As, unsigned short* Bs, f32x4_t acc[4][4], int mBase, int nBase)
{
    const int tid  = threadIdx.x;
    const int lane = tid & 63;
    const int wv   = tid >> 6;
    const int quad = lane >> 4;
    const int l16  = lane & 15;
    const int wm   = (wv >> 1) * 64;
    const int wn   = (wv & 1) * 64;

    f32x4_t zero = {0.f, 0.f, 0.f, 0.f};
#pragma unroll
    for (int tm = 0; tm < 4; tm++)
#pragma unroll
        for (int tn = 0; tn < 4; tn++)
            acc[tm][tn] = zero;

    for (int kt = 0; kt < 768; kt += 64) {
#pragma unroll
        for (int i = 0; i < 4; i++) {
            int cbase = i * 256 + wv * 64;       // wave-uniform chunk base
            int ci = cbase + lane;               // 16B chunk 0..1023
            int r = ci >> 3;
            int koff = (((ci & 7) ^ (r & 7)) << 3);   // swizzled granule
            __builtin_amdgcn_global_load_lds(
                AS1C(A + (size_t)(mBase + r) * 768 + kt + koff),
                AS3(As + cbase * 8), 16, 0, 0);
            __builtin_amdgcn_global_load_lds(
                AS1C(Bt + (size_t)(nBase + r) * 768 + kt + koff),
                AS3(Bs + cbase * 8), 16, 0, 0);
        }
        __syncthreads();
#pragma unroll
        for (int ks = 0; ks < 2; ks++) {
            bf16x8_t af[4], bfv[4];
#pragma unroll
            for (int tm = 0; tm < 4; tm++)
                af[tm] = *(const bf16x8_t*)(As + (wm + tm * 16 + l16) * 64 +
                                            (((ks * 4 + quad) ^ (l16 & 7)) << 3));
#pragma unroll
            for (int tn = 0; tn < 4; tn++)
                bfv[tn] = *(const bf16x8_t*)(Bs + (wn + tn * 16 + l16) * 64 +
                                             (((ks * 4 + quad) ^ (l16 & 7)) << 3));
#pragma unroll
            for (int tm = 0; tm < 4; tm++)
#pragma unroll
                for (int tn = 0; tn < 4; tn++)
                    acc[tm][tn] = __builtin_amdgcn_mfma_f32_16x16x32_bf16(
                        af[tm], bfv[tn], acc[tm][tn], 0, 0, 0);
        }
        __syncthreads();
    }
}

// GEMM1: qkv = x @ w_attn + b_attn. 1D grid 1152, XCD-sliced. Natural VGPR (112);
// no min-waves bound (r7: (256,5) -> VGPR 48, spills, 90 us).
__global__ __launch_bounds__(256) void gemm_qkv(
    const unsigned short* __restrict__ x, const unsigned short* __restrict__ waT,
    const float* __restrict__ b_attn,
    unsigned short* __restrict__ qbuf, unsigned short* __restrict__ kbuf,
    unsigned short* __restrict__ vbuf)
{
    __shared__ __align__(16) unsigned short As[128 * 64];
    __shared__ __align__(16) unsigned short Bs[128 * 64];
    f32x4_t acc[4][4];
    const int lid = blockIdx.x;
    const int xcd = lid & 7;
    const int j = lid >> 3;                 // 0..143
    const int mTile = xcd * 8 + (j & 7);    // 0..63
    const int nTile = j >> 3;               // 0..17
    const int mBase = mTile * 128;
    const int nBase = nTile * 128;
    gemm128_core(x, waT, As, Bs, acc, mBase, nBase);

    const int tid = threadIdx.x;
    const int lane = tid & 63, wv = tid >> 6;
    const int quad = lane >> 4, l16 = lane & 15;
    const int wm = (wv >> 1) * 64, wn = (wv & 1) * 64;
    const int part = nTile / 6;             // 0=q 1=k 2=v (block-uniform)

#pragma unroll
    for (int tn = 0; tn < 4; tn++) {
        int n = nBase + wn + tn * 16 + l16;     // 0..2303
        float bv = b_attn[n];
        int f = n - part * 768;
        int hh = f >> 6, d = f & 63;
        if (part == 2) {
#pragma unroll
            for (int tm = 0; tm < 4; tm++) {
                int t0 = mBase + wm + tm * 16 + quad * 4;   // 4-aligned, no b-crossing
                int bb = t0 >> 10, tt = t0 & 1023;
                ushort4 pk;
                pk.x = f2bf(acc[tm][tn][0] + bv);
                pk.y = f2bf(acc[tm][tn][1] + bv);
                pk.z = f2bf(acc[tm][tn][2] + bv);
                pk.w = f2bf(acc[tm][tn][3] + bv);
                *(ushort4*)(vbuf + ((size_t)(bb * N_HEAD + hh) * HDIM + d) * SEQ_T + tt) = pk;
            }
        } else {
            const float scale = (part == 0) ? L2E : 1.f;
            unsigned short* dst = (part == 0) ? qbuf : kbuf;
#pragma unroll
            for (int tm = 0; tm < 4; tm++) {
#pragma unroll
                for (int i = 0; i < 4; i++) {
                    int row = mBase + wm + tm * 16 + quad * 4 + i;
                    int bb = row >> 10, tt = row & 1023;
                    dst[((size_t)(bb * N_HEAD + hh) * SEQ_T + tt) * HDIM + d] =
                        f2bf((acc[tm][tn][i] + bv) * scale);
                }
            }
        }
    }
}

// mask + exp2 + l-accumulate + pack to bf16 pairs (pure VALU, no memory ops)
__device__ __forceinline__ void mask_exp_pack(
    f32x4_t s[4], int diag, int qloc, int quad,
    float& lsum, unsigned int u[4][2])
{
    if (diag) {
#pragma unroll
        for (int c = 0; c < 4; c++)
#pragma unroll
            for (int i = 0; i < 4; i++)
                if (c * 16 + quad * 4 + i > qloc) s[c][i] = -1e30f;
    }
    float p[4][4];
#pragma unroll
    for (int c = 0; c < 4; c++)
#pragma unroll
        for (int i = 0; i < 4; i++)
            p[c][i] = exp2f(s[c][i]);
#pragma unroll
    for (int c = 0; c < 4; c++)
        lsum += (p[c][0] + p[c][1]) + (p[c][2] + p[c][3]);
#pragma unroll
    for (int c = 0; c < 4; c++)
#pragma unroll
        for (int i2 = 0; i2 < 2; i2++)
            u[c][i2] = (unsigned int)f2bf(p[c][2 * i2]) |
                       ((unsigned int)f2bf(p[c][2 * i2 + 1]) << 16);
}

__device__ __forceinline__ void p_write(
    unsigned short* pw, const unsigned int u[4][2], int quad, int l16)
{
#pragma unroll
    for (int c = 0; c < 4; c++)
#pragma unroll
        for (int i2 = 0; i2 < 2; i2++) {
            int g = c * 2 + (quad >> 1);
            *(unsigned int*)(pw + l16 * 64 + ((g ^ (l16 & 7)) << 3) +
                             4 * (quad & 1) + 2 * i2) = u[c][i2];
        }
}

// Fused causal attention. Block = paired q-tiles (t, 15-t). Grid (96 bh, 8 t):
// lid%8 = bh%8 -> all 8 pair-blocks of a (b,h) share one XCD (K/V hot in its L2).
// Tiles interleaved so tile A's exp/pack VALU hides tile B's P write->read latency.
__global__ __launch_bounds__(256, 3) void attn_fused(
    const unsigned short* __restrict__ qb, const unsigned short* __restrict__ kb,
    const unsigned short* __restrict__ vb, unsigned short* __restrict__ attb)
{
    __shared__ __align__(16) unsigned short Kbuf[2][64 * 64];
    __shared__ __align__(16) unsigned short Vbuf[2][64 * 64];   // V^T tiles [d][s]
    __shared__ __align__(16) unsigned short Psh[4][16 * 64];

    const int bhx = blockIdx.x;     // 0..95
    const int t   = blockIdx.y;     // 0..7; tiles t and 15-t
    const int h = bhx % N_HEAD;
    const int b = bhx / N_HEAD;
    const int tid = threadIdx.x;
    const int lane = tid & 63, wv = tid >> 6;
    const int quad = lane >> 4, l16 = lane & 15;
    const int tB = 15 - t, kmax = 15 - t;
    const int qloc = wv * 16 + l16;

    const size_t bh = (size_t)(b * N_HEAD + h);
    const unsigned short* kbase = kb + bh * SEQ_T * HDIM;
    const unsigned short* vbase = vb + bh * HDIM * SEQ_T;
    const unsigned short* qpt   = qb + bh * SEQ_T * HDIM;

    const int j0 = wv * 128 + lane, j1 = j0 + 64;
    const int r0 = j0 >> 3, g0 = (j0 & 7) ^ (r0 & 7);
    const int r1 = j1 >> 3, g1 = (j1 & 7) ^ (r1 & 7);
    const int rgK0 = r0 * 64 + g0 * 8,   rgK1 = r1 * 64 + g1 * 8;
    const int rgV0 = r0 * 1024 + g0 * 8, rgV1 = r1 * 1024 + g1 * 8;
    const int ldsc0 = (wv * 128) * 8, ldsc1 = (wv * 128 + 64) * 8;  // wave-uniform

    bf16x8_t qfA[2], qfB[2];
    {
        const unsigned short* qa  = qpt + (size_t)(t * 64 + qloc) * HDIM;
        const unsigned short* qbp = qpt + (size_t)(tB * 64 + qloc) * HDIM;
#pragma unroll
        for (int kc = 0; kc < 2; kc++) {
            qfA[kc] = *(const bf16x8_t*)(qa + kc * 32 + quad * 8);
            qfB[kc] = *(const bf16x8_t*)(qbp + kc * 32 + quad * 8);
        }
    }

    f32x4_t zero = {0.f, 0.f, 0.f, 0.f};
    f32x4_t oA[4], oB[4];
#pragma unroll
    for (int c = 0; c < 4; c++) { oA[c] = zero; oB[c] = zero; }
    float lA = 0.f, lB = 0.f;

    __builtin_amdgcn_global_load_lds(AS1C(kbase + rgK0), AS3(&Kbuf[0][0] + ldsc0), 16, 0, 0);
    __builtin_amdgcn_global_load_lds(AS1C(kbase + rgK1), AS3(&Kbuf[0][0] + ldsc1), 16, 0, 0);
    __builtin_amdgcn_global_load_lds(AS1C(vbase + rgV0), AS3(&Vbuf[0][0] + ldsc0), 16, 0, 0);
    __builtin_amdgcn_global_load_lds(AS1C(vbase + rgV1), AS3(&Vbuf[0][0] + ldsc1), 16, 0, 0);
    __syncthreads();

    for (int kt = 0; kt <= kmax; kt++) {
        const int cur = kt & 1, nxt = cur ^ 1;
        if (kt < kmax) {
            const unsigned short* kp = kbase + (kt + 1) * 4096;
            const unsigned short* vp = vbase + (kt + 1) * 64;
            __builtin_amdgcn_global_load_lds(AS1C(kp + rgK0), AS3(&Kbuf[nxt][0] + ldsc0), 16, 0, 0);
            __builtin_amdgcn_global_load_lds(AS1C(kp + rgK1), AS3(&Kbuf[nxt][0] + ldsc1), 16, 0, 0);
            __builtin_amdgcn_global_load_lds(AS1C(vp + rgV0), AS3(&Vbuf[nxt][0] + ldsc0), 16, 0, 0);
            __builtin_amdgcn_global_load_lds(AS1C(vp + rgV1), AS3(&Vbuf[nxt][0] + ldsc1), 16, 0, 0);
        }

        const unsigned short* Kc = &Kbuf[cur][0];
        const unsigned short* Vc = &Vbuf[cur][0];
        const int doA = (kt <= t);

        bf16x8_t vf[4][2];
#pragma unroll
        for (int nc = 0; nc < 4; nc++)
#pragma unroll
            for (int kc = 0; kc < 2; kc++)
                vf[nc][kc] = *(const bf16x8_t*)(Vc + (nc * 16 + l16) * 64 +
                                                (((kc * 4 + quad) ^ (l16 & 7)) << 3));

        f32x4_t sB[4], sA[4];
#pragma unroll
        for (int c = 0; c < 4; c++) {
            bf16x8_t kf0 = *(const bf16x8_t*)(Kc + (c * 16 + l16) * 64 +
                                              ((quad ^ (l16 & 7)) << 3));
            bf16x8_t kf1 = *(const bf16x8_t*)(Kc + (c * 16 + l16) * 64 +
                                              (((4 + quad) ^ (l16 & 7)) << 3));
            sB[c] = __builtin_amdgcn_mfma_f32_16x16x32_bf16(kf0, qfB[0], zero, 0, 0, 0);
            sB[c] = __builtin_amdgcn_mfma_f32_16x16x32_bf16(kf1, qfB[1], sB[c], 0, 0, 0);
            if (doA) {
                sA[c] = __builtin_amdgcn_mfma_f32_16x16x32_bf16(kf0, qfA[0], zero, 0, 0, 0);
                sA[c] = __builtin_amdgcn_mfma_f32_16x16x32_bf16(kf1, qfA[1], sA[c], 0, 0, 0);
            }
        }

        unsigned short* pw = &Psh[wv][0];
        unsigned int uB[4][2], uA[4][2];

        mask_exp_pack(sB, kt == tB, qloc, quad, lB, uB);
        __asm__ __volatile__("" ::: "memory");
        p_write(pw, uB, quad, l16);                    // P_B -> LDS
        if (doA)
            mask_exp_pack(sA, kt == t, qloc, quad, lA, uA);  // VALU hides P_B drain
        __asm__ __volatile__("" ::: "memory");
        bf16x8_t pfB[2];
#pragma unroll
        for (int kc = 0; kc < 2; kc++)
            pfB[kc] = *(const bf16x8_t*)(pw + l16 * 64 + (((kc * 4 + quad) ^ (l16 & 7)) << 3));
        __asm__ __volatile__("" ::: "memory");         // keep P_A writes after P_B reads
#pragma unroll
        for (int kc = 0; kc < 2; kc++)
#pragma unroll
            for (int nc = 0; nc < 4; nc++)
                oB[nc] = __builtin_amdgcn_mfma_f32_16x16x32_bf16(pfB[kc], vf[nc][kc], oB[nc], 0, 0, 0);
        if (doA) {
            p_write(pw, uA, quad, l16);                // P_A -> LDS (PV_B MFMAs overlap)
            __asm__ __volatile__("" ::: "memory");
            bf16x8_t pfA[2];
#pragma unroll
            for (int kc = 0; kc < 2; kc++)
                pfA[kc] = *(const bf16x8_t*)(pw + l16 * 64 + (((kc * 4 + quad) ^ (l16 & 7)) << 3));
#pragma unroll
            for (int kc = 0; kc < 2; kc++)
#pragma unroll
                for (int nc = 0; nc < 4; nc++)
                    oA[nc] = __builtin_amdgcn_mfma_f32_16x16x32_bf16(pfA[kc], vf[nc][kc], oA[nc], 0, 0, 0);
        }
        __syncthreads();
    }

    lA += __shfl_xor(lA, 16); lA += __shfl_xor(lA, 32);
    lB += __shfl_xor(lB, 16); lB += __shfl_xor(lB, 32);
    float invA = 1.f / lA, invB = 1.f / lB;
    float iA[4], iB[4];
#pragma unroll
    for (int i = 0; i < 4; i++) {
        iA[i] = __shfl(invA, quad * 4 + i);
        iB[i] = __shfl(invB, quad * 4 + i);
    }

#pragma unroll
    for (int nc = 0; nc < 4; nc++)
#pragma unroll
        for (int i = 0; i < 4; i++) {
            int rowA = t * 64 + wv * 16 + quad * 4 + i;
            int rowB = tB * 64 + wv * 16 + quad * 4 + i;
            int col = h * HDIM + nc * 16 + l16;
            attb[((size_t)b * SEQ_T + rowA) * CDIM + col] = f2bf(oA[nc][i] * iA[i]);
            attb[((size_t)b * SEQ_T + rowB) * CDIM + col] = f2bf(oB[nc][i] * iB[i]);
        }
}

// GEMM2: out(fp32) = att @ w_proj + b_proj. 64x128 tiles -> 768 blocks (3+/CU).
// Chunk math: one 64-halfword row = 8 sixteen-byte granules. A: 64 rows = 512
// chunks (2 staging iters); B: 128 rows = 1024 chunks (4 iters). [r9 bug: halved]
__global__ __launch_bounds__(256) void gemm_proj(
    const unsigned short* __restrict__ attb, const unsigned short* __restrict__ wpT,
    const float* __restrict__ b_proj, float* __restrict__ out)
{
    __shared__ __align__(16) unsigned short As[64 * 64];    // 8 KB
    __shared__ __align__(16) unsigned short Bs[128 * 64];   // 16 KB
    const int lid = blockIdx.x;             // 0..767
    const int xcd = lid & 7;
    const int j = lid >> 3;                 // 0..95
    const int mTile = xcd * 16 + (j & 15);  // 0..127
    const int nTile = j >> 4;               // 0..5
    const int mBase = mTile * 64;
    const int nBase = nTile * 128;

    const int tid  = threadIdx.x;
    const int lane = tid & 63;
    const int wv   = tid >> 6;
    const int quad = lane >> 4;
    const int l16  = lane & 15;
    const int wm   = (wv >> 1) * 32;
    const int wn   = (wv & 1) * 64;

    f32x4_t zero = {0.f, 0.f, 0.f, 0.f};
    f32x4_t acc[2][4];
#pragma unroll
    for (int tm = 0; tm < 2; tm++)
#pragma unroll
        for (int tn = 0; tn < 4; tn++)
            acc[tm][tn] = zero;

    for (int kt = 0; kt < 768; kt += 64) {
#pragma unroll
        for (int i = 0; i < 2; i++) {   // A tile: 512 chunks (64 rows x 8)
            int cbase = i * 256 + wv * 64;
            int ci = cbase + lane;
            int r = ci >> 3;
            int koff = (((ci & 7) ^ (r & 7)) << 3);
            __builtin_amdgcn_global_load_lds(
                AS1C(attb + (size_t)(mBase + r) * 768 + kt + koff),
                AS3(As + cbase * 8), 16, 0, 0);
        }
#pragma unroll
        for (int i = 0; i < 4; i++) {   // B tile: 1024 chunks (128 rows x 8)
            int cbase = i * 256 + wv * 64;
            int ci = cbase + lane;
            int r = ci >> 3;
            int koff = (((ci & 7) ^ (r & 7)) << 3);
            __builtin_amdgcn_global_load_lds(
                AS1C(wpT + (size_t)(nBase + r) * 768 + kt + koff),
                AS3(Bs + cbase * 8), 16, 0, 0);
        }
        __syncthreads();
#pragma unroll
        for (int ks = 0; ks < 2; ks++) {
            bf16x8_t af[2], bfv[4];
#pragma unroll
            for (int tm = 0; tm < 2; tm++)
                af[tm] = *(const bf16x8_t*)(As + (wm + tm * 16 + l16) * 64 +
                                            (((ks * 4 + quad) ^ (l16 & 7)) << 3));
#pragma unroll
            for (int tn = 0; tn < 4; tn++)
                bfv[tn] = *(const bf16x8_t*)(Bs + (wn + tn * 16 + l16) * 64 +
                                             (((ks * 4 + quad) ^ (l16 & 7)) << 3));
#pragma unroll
            for (int tm = 0; tm < 2; tm++)
#pragma unroll
                for (int tn = 0; tn < 4; tn++)
                    acc[tm][tn] = __builtin_amdgcn_mfma_f32_16x16x32_bf16(
                        af[tm], bfv[tn], acc[tm][tn], 0, 0, 0);
        }
        __syncthreads();
    }

#pragma unroll
    for (int tn = 0; tn < 4; tn++) {
        int n = nBase + wn + tn * 16 + l16;
        float bv = b_proj[n];
#pragma unroll
        for (int tm = 0; tm < 2; tm++)
#pragma unroll
            for (int i = 0; i < 4; i++) {
                int row = mBase + wm + tm * 16 + quad * 4 + i;
                out[(size_t)row * CDIM + n] = acc[tm][tn][i] + bv;
            }
    }
}

extern "C" void kernel_launch(void* const* d_in, const int* in_sizes, int n_in,
                              void* d_out, int out_size, void* d_ws, size_t ws_size,
                              hipStream_t stream) {
    const float* x      = (const float*)d_in[0];  // [8,1024,768] fp32
    const float* w_attn = (const float*)d_in[1];  // [768,2304]   fp32
    const float* b_attn = (const float*)d_in[2];  // [2304]       fp32
    const float* w_proj = (const float*)d_in[3];  // [768,768]    fp32
    const float* b_proj = (const float*)d_in[4];  // [768]        fp32
    float* out = (float*)d_out;                   // [8,1024,768] fp32

    unsigned short* ws   = (unsigned short*)d_ws;
    unsigned short* waT  = ws;                    // [2304][768] bf16
    unsigned short* wpT  = waT + 1769472;         // [768][768]  bf16
    unsigned short* xbf  = wpT + 589824;          // [8192][768] bf16
    unsigned short* qbuf = xbf + 6291456;         // [B,H,T,D] (log2e-scaled)
    unsigned short* kbuf = qbuf + 6291456;        // [B,H,T,D]
    unsigned short* vbuf = kbuf + 6291456;        // [B,H,D,T]
    unsigned short* attb = vbuf + 6291456;        // [B,T,C]
    // ws use: 67,633,152 bytes

    prep<<<dim3(8448), 256, 0, stream>>>((const float4*)x, (ushort4*)xbf,
                                         w_attn, waT, w_proj, wpT);
    gemm_qkv<<<dim3(1152), 256, 0, stream>>>(xbf, waT, b_attn, qbuf, kbuf, vbuf);
    attn_fused<<<dim3(96, 8), 256, 0, stream>>>(qbuf, kbuf, vbuf, attb);
    gemm_proj<<<dim3(768), 256, 0, stream>>>(attb, wpT, b_proj, out);
}